// Round 21
// baseline (98.415 us; speedup 1.0000x reference)
//
#include <hip/hip_runtime.h>

typedef __attribute__((ext_vector_type(4))) float f32x4;
typedef __attribute__((ext_vector_type(16))) float f32x16;
typedef __attribute__((ext_vector_type(8))) __bf16 bf16x8;
typedef __attribute__((ext_vector_type(4))) __bf16 bf16x4;
typedef __attribute__((ext_vector_type(4))) unsigned u32x4;
typedef __attribute__((ext_vector_type(2))) unsigned u32x2;

static __device__ __forceinline__ f32x4 mfma16(bf16x8 a, bf16x8 b, f32x4 c) {
    return __builtin_amdgcn_mfma_f32_16x16x32_bf16(a, b, c, 0, 0, 0);
}
static __device__ __forceinline__ f32x16 mfma32(bf16x8 a, bf16x8 b, f32x16 c) {
    return __builtin_amdgcn_mfma_f32_32x32x16_bf16(a, b, c, 0, 0, 0);
}
static __device__ __forceinline__ unsigned pk_bf16(float a, float b) {
    unsigned lo = __builtin_bit_cast(unsigned short, (__bf16)a);
    unsigned hh = __builtin_bit_cast(unsigned short, (__bf16)b);
    return lo | (hh << 16);
}

// Q pre-scale: 1/sqrt(64) * log2(e)  (exp2 applied directly to S, shift-free)
#define QSCALE 0.18033688f
#define FENCE() asm volatile("" ::: "memory")
#define SYNCB()                          \
    do {                                 \
        FENCE();                         \
        __builtin_amdgcn_s_barrier();    \
        FENCE();                         \
    } while (0)

// ---------------------------------------------------------------------------
// 1) fused prep: x cvt -> bf16 (blocks 0..4095), w_qkv transpose
//    (4096..7167), w_out transpose (7168..8191)
// ---------------------------------------------------------------------------
__global__ __launch_bounds__(256) void prep_all(const float* __restrict__ x,
                                                __bf16* __restrict__ xb,
                                                const float* __restrict__ wq,
                                                __bf16* __restrict__ wqT,
                                                const float* __restrict__ wo,
                                                __bf16* __restrict__ woT) {
    __shared__ float t[32][33];
    int bid = blockIdx.x, tid = threadIdx.x;
    if (bid < 4096) {
        int i = bid * 256 + tid;
        f32x4 v = ((const f32x4*)x)[i];
        bf16x4 o;
#pragma unroll
        for (int j = 0; j < 4; j++) o[j] = (__bf16)v[j];
        ((bf16x4*)xb)[i] = o;
        return;
    }
    const float* in;
    __bf16* out;
    int R, C, bx, by;
    if (bid < 4096 + 3072) {
        int b2 = bid - 4096;
        in = wq; out = wqT; R = 1024; C = 3072;
        bx = (b2 % 96) * 32; by = (b2 / 96) * 32;
    } else {
        int b2 = bid - 7168;
        in = wo; out = woT; R = 1024; C = 1024;
        bx = (b2 % 32) * 32; by = (b2 / 32) * 32;
    }
    int tx = tid & 31, ty = tid >> 5;  // 32 x 8
#pragma unroll
    for (int k = 0; k < 32; k += 8)
        t[ty + k][tx] = in[(size_t)(by + ty + k) * C + bx + tx];
    __syncthreads();
#pragma unroll
    for (int k = 0; k < 32; k += 8)
        out[(size_t)(bx + ty + k) * R + by + tx] = (__bf16)t[tx][ty + k];
}

// ---------------------------------------------------------------------------
// 3a) QKV GEMM, 256x256 tile, 8-phase counted-vmcnt schedule, conflict-free
//     LDS swizzle f(r) = (r>>1)&3 (round-17 proven: bank conflicts -> 0).
// ---------------------------------------------------------------------------
__global__ __launch_bounds__(512, 2) void qkv_gemm8(const __bf16* __restrict__ A,
                                                    const __bf16* __restrict__ Bt,
                                                    __bf16* __restrict__ Qf,
                                                    __bf16* __restrict__ Kf,
                                                    __bf16* __restrict__ Vf) {
    const int K = 1024, NT = 16, MT = 12;
    __shared__ __attribute__((aligned(16))) __bf16 smem[65536];  // 128 KiB
    int tid = threadIdx.x;
    int w = tid >> 6, lane = tid & 63;
    int lrow = lane & 15, lgrp = lane >> 4;
    int wm = w >> 2, wn = w & 3;
    int bid = blockIdx.x;
    int swz = (bid & 7) * 24 + (bid >> 3);          // 192 % 8 == 0: bijective
    int m0 = (swz % MT) * 256, n0 = (swz / MT) * 256;

    int schunk = ((lane & 3) ^ ((lane >> 3) & 3)) * 8;  // elements
    const __bf16* aS[2];
    const __bf16* bS[2];
    int dstRow[2];
#pragma unroll
    for (int l = 0; l < 2; l++) {
        int r = w * 32 + l * 16 + (lane >> 2);
        aS[l] = A + (size_t)(m0 + r) * K + schunk;
        bS[l] = Bt + (size_t)(n0 + r) * K + schunk;
        dstRow[l] = (w * 32 + l * 16) * 64;  // byte offset of row block
    }

    auto STAGE = [&](int h, int tt) {
        int tc = tt < NT ? tt : NT - 1;
        int op = h & 1, kh = h >> 1;
        int base = ((tt & 1) << 16) + (kh << 15) + (op << 14);
#pragma unroll
        for (int l = 0; l < 2; l++) {
            const __bf16* src = (op ? bS[l] : aS[l]) + tc * 64 + kh * 32;
            __builtin_amdgcn_global_load_lds(
                (const __attribute__((address_space(1))) void*)src,
                (__attribute__((address_space(3))) void*)(smem +
                                                          ((base + dstRow[l]) >> 1)),
                16, 0, 0);
        }
    };

    int swzsel = (lgrp ^ ((lrow >> 1) & 3)) << 4;  // byte offset of chunk slot
    auto RDA = [&](int buf, int kk, int row) {
        int off = (buf << 16) + (kk << 15) + row * 64 + swzsel;
        return *(const bf16x8*)(smem + (off >> 1));
    };
    auto RDB = [&](int buf, int kk, int row) {
        int off = (buf << 16) + (kk << 15) + 16384 + row * 64 + swzsel;
        return *(const bf16x8*)(smem + (off >> 1));
    };

    f32x4 acc[8][4];
#pragma unroll
    for (int i = 0; i < 8; i++)
#pragma unroll
        for (int j = 0; j < 4; j++) acc[i][j] = (f32x4){0.f, 0.f, 0.f, 0.f};
    bf16x8 bfr[4];

    STAGE(0, 0); STAGE(1, 0); STAGE(2, 0); STAGE(3, 0);
    STAGE(0, 1); STAGE(1, 1);
    asm volatile("s_waitcnt vmcnt(8)" ::: "memory");
    SYNCB();

#define PH(T, KKv, MHv, SH, ST, DOVM)                                          \
    {                                                                          \
        bf16x8 af[4];                                                          \
        if (MHv == 0) {                                                        \
            _Pragma("unroll") for (int nt = 0; nt < 4; nt++) bfr[nt] =         \
                RDB((T) & 1, KKv, wn * 64 + nt * 16 + lrow);                   \
        }                                                                      \
        _Pragma("unroll") for (int i = 0; i < 4; i++) af[i] =                  \
            RDA((T) & 1, KKv, wm * 128 + (MHv * 4 + i) * 16 + lrow);           \
        STAGE(SH, ST);                                                         \
        if (DOVM) asm volatile("s_waitcnt vmcnt(8)" ::: "memory");             \
        SYNCB();                                                               \
        asm volatile("s_waitcnt lgkmcnt(0)" ::: "memory");                     \
        __builtin_amdgcn_sched_barrier(0);                                     \
        __builtin_amdgcn_s_setprio(1);                                         \
        _Pragma("unroll") for (int i = 0; i < 4; i++)                          \
            _Pragma("unroll") for (int nt = 0; nt < 4; nt++)                   \
                acc[MHv * 4 + i][nt] =                                         \
                    mfma16(af[i], bfr[nt], acc[MHv * 4 + i][nt]);              \
        __builtin_amdgcn_s_setprio(0);                                         \
        SYNCB();                                                               \
    }

#pragma unroll 2
    for (int t = 0; t < NT; ++t) {
        PH(t, 0, 0, 2, t + 1, 0);
        PH(t, 0, 1, 3, t + 1, 1);
        PH(t, 1, 0, 0, t + 2, 0);
        PH(t, 1, 1, 1, t + 2, 1);
    }
#undef PH

    asm volatile("s_waitcnt vmcnt(0)" ::: "memory");
    SYNCB();

#pragma unroll
    for (int mt = 0; mt < 8; mt++) {
#pragma unroll
        for (int nt = 0; nt < 4; nt++) {
            int f0 = m0 + wm * 128 + mt * 16 + lgrp * 4;
            int t = n0 + wn * 64 + nt * 16 + lrow;
            int which = f0 >> 10, hn = f0 & 1023;
            int h = hn >> 6, d0 = hn & 63;
            int b = t >> 11, li = t & 2047;
            int bh = b * 16 + h, c = li >> 5, tl = li & 31;
            size_t bhbase = (size_t)bh * 131072;
            if (which == 2) {
                int ks = tl >> 4, hv = (tl >> 3) & 1, jv = tl & 7;
                size_t base =
                    bhbase + ((size_t)(c * 4 + ks * 2 + hv) * 64 + d0) * 8 + jv;
#pragma unroll
                for (int r = 0; r < 4; r++)
                    Vf[base + (size_t)r * 8] = (__bf16)acc[mt][nt][r];
            } else {
                int st = d0 >> 4, hv = (d0 >> 3) & 1, j0 = d0 & 7;
                size_t idx =
                    bhbase + ((size_t)(c * 8 + st * 2 + hv) * 32 + tl) * 8 + j0;
                bf16x4 pv;
                if (which == 0) {
#pragma unroll
                    for (int r = 0; r < 4; r++)
                        pv[r] = (__bf16)(acc[mt][nt][r] * QSCALE);
                    *(bf16x4*)(Qf + idx) = pv;
                } else {
#pragma unroll
                    for (int r = 0; r < 4; r++) pv[r] = (__bf16)acc[mt][nt][r];
                    *(bf16x4*)(Kf + idx) = pv;
                }
            }
        }
    }
}

// ---------------------------------------------------------------------------
// 3b) bf16 GEMM (proven 2-barrier structure), BM=64 x 128, out projection.
// ---------------------------------------------------------------------------
#define BN 128
#define BKG 64

template <int MODE, int BMv>
__global__ __launch_bounds__(256) void gemm_bt(const __bf16* __restrict__ A,
                                               const __bf16* __restrict__ Bt,
                                               int M, int N, int K,
                                               float* __restrict__ Cout) {
    constexpr int nMt = BMv / 32;
    __shared__ __attribute__((aligned(16))) __bf16 As[BMv * BKG];
    __shared__ __attribute__((aligned(16))) __bf16 Bs[BN * BKG];
    int tid = threadIdx.x;
    int wave = tid >> 6, lane = tid & 63;
    int lrow = lane & 15, lgrp = lane >> 4;
    int bid = blockIdx.x;
    int chunk = gridDim.x >> 3;
    int swz = (bid & 7) * chunk + (bid >> 3);
    int nbx = N >> 7;
    int m0 = (swz / nbx) * BMv;
    int n0 = (swz % nbx) * BN;
    int wm = (wave >> 1) * (BMv / 2);
    int wn = (wave & 1) * 64;

    f32x4 acc[nMt][4];
#pragma unroll
    for (int i = 0; i < nMt; i++)
#pragma unroll
        for (int j = 0; j < 4; j++) acc[i][j] = (f32x4){0.f, 0.f, 0.f, 0.f};

    int srow = tid >> 3;
    int gch = (tid & 7) ^ (srow & 7);
    const __bf16* aSrc = A + (size_t)(m0 + srow) * K + gch * 8;
    const __bf16* bSrc = Bt + (size_t)(n0 + srow) * K + gch * 8;

    for (int k0 = 0; k0 < K; k0 += BKG) {
#pragma unroll
        for (int c = 0; c < BMv / 32; c++) {
            __builtin_amdgcn_global_load_lds(
                (const __attribute__((address_space(1))) void*)(aSrc + k0 + (size_t)c * 32 * K),
                (__attribute__((address_space(3))) void*)(As + (c * 256 + wave * 64) * 8),
                16, 0, 0);
        }
#pragma unroll
        for (int c = 0; c < 4; c++) {
            __builtin_amdgcn_global_load_lds(
                (const __attribute__((address_space(1))) void*)(bSrc + k0 + (size_t)c * 32 * K),
                (__attribute__((address_space(3))) void*)(Bs + (c * 256 + wave * 64) * 8),
                16, 0, 0);
        }
        __syncthreads();
#pragma unroll
        for (int kk = 0; kk < 2; kk++) {
            bf16x8 af[nMt], bfr[4];
#pragma unroll
            for (int mt = 0; mt < nMt; mt++) {
                int row = wm + mt * 16 + lrow;
                int slot = row * 8 + ((4 * kk + lgrp) ^ (row & 7));
                af[mt] = *(const bf16x8*)(As + slot * 8);
            }
#pragma unroll
            for (int nt = 0; nt < 4; nt++) {
                int row = wn + nt * 16 + lrow;
                int slot = row * 8 + ((4 * kk + lgrp) ^ (row & 7));
                bfr[nt] = *(const bf16x8*)(Bs + slot * 8);
            }
#pragma unroll
            for (int mt = 0; mt < nMt; mt++)
#pragma unroll
                for (int nt = 0; nt < 4; nt++)
                    acc[mt][nt] = mfma16(af[mt], bfr[nt], acc[mt][nt]);
        }
        __syncthreads();
    }

#pragma unroll
    for (int mt = 0; mt < nMt; mt++) {
#pragma unroll
        for (int nt = 0; nt < 4; nt++) {
            int f0 = m0 + wm + mt * 16 + lgrp * 4;
            int t = n0 + wn + nt * 16 + lrow;
            *(f32x4*)(Cout + (size_t)t * M + f0) = acc[mt][nt];
        }
    }
}

// ---------------------------------------------------------------------------
// 4) Causal flash attention v17: round-18 proven kernel (fused exp2->pack,
//    f32 slabs, two-stage combine, MFMA row-sum) with ONE isolated change:
//    alternating heavy/light strip dispatch (bijective on 0..63) to smooth
//    per-CU makespan at the tail.
// ---------------------------------------------------------------------------
template <bool MASKED>
static __device__ __forceinline__ void attn_chunk(
    int c, int ql, int hi, const __bf16* __restrict__ Kp,
    const __bf16* __restrict__ Vp, const bf16x8 (&qf)[4], bf16x8 ones,
    f32x16& o0, f32x16& o1, f32x16& lsa) {
    const __bf16* kb = Kp + ((size_t)c * 8 + hi) * 256 + ql * 8;
    bf16x8 kf[4];
#pragma unroll
    for (int st = 0; st < 4; st++) kf[st] = *(const bf16x8*)(kb + st * 512);
    const __bf16* vb = Vp + ((size_t)c * 4 + hi) * 512 + ql * 8;
    bf16x8 v00 = *(const bf16x8*)(vb);
    bf16x8 v01 = *(const bf16x8*)(vb + 256);
    bf16x8 v10 = *(const bf16x8*)(vb + 1024);
    bf16x8 v11 = *(const bf16x8*)(vb + 1280);

    f32x16 sa;
#pragma unroll
    for (int r = 0; r < 16; r++) sa[r] = 0.f;
#pragma unroll
    for (int st = 0; st < 4; st++) sa = mfma32(kf[st], qf[st], sa);

    // fused exp2 + pack (no p[16] array; identical values/order)
    unsigned w[8];
#pragma unroll
    for (int i = 0; i < 8; i++) {
        float a = sa[2 * i], b = sa[2 * i + 1];
        if (MASKED) {
            int ra = 2 * i, rb = 2 * i + 1;
            if (((ra & 3) + 8 * (ra >> 2) + 4 * hi) > ql) a = -1e30f;
            if (((rb & 3) + 8 * (rb >> 2) + 4 * hi) > ql) b = -1e30f;
        }
        w[i] = pk_bf16(__builtin_amdgcn_exp2f(a), __builtin_amdgcn_exp2f(b));
    }
    u32x2 r02 = __builtin_amdgcn_permlane32_swap(w[0], w[2], false, false);
    u32x2 r13 = __builtin_amdgcn_permlane32_swap(w[1], w[3], false, false);
    u32x2 r46 = __builtin_amdgcn_permlane32_swap(w[4], w[6], false, false);
    u32x2 r57 = __builtin_amdgcn_permlane32_swap(w[5], w[7], false, false);
    bf16x8 pa0 = __builtin_bit_cast(bf16x8, (u32x4){r02[0], r13[0], r02[1], r13[1]});
    bf16x8 pa1 = __builtin_bit_cast(bf16x8, (u32x4){r46[0], r57[0], r46[1], r57[1]});

    o0 = mfma32(pa0, v00, o0);
    o1 = mfma32(pa0, v01, o1);
    lsa = mfma32(pa0, ones, lsa);
    o0 = mfma32(pa1, v10, o0);
    o1 = mfma32(pa1, v11, o1);
    lsa = mfma32(pa1, ones, lsa);
}

__global__ __launch_bounds__(256, 4) void attn_fwd17(const __bf16* __restrict__ Qf,
                                                     const __bf16* __restrict__ Kf,
                                                     const __bf16* __restrict__ Vf,
                                                     __bf16* __restrict__ Ob) {
    __shared__ float comb[2][64][49];  // 25.1 KB, f32 precision
    int tid = threadIdx.x;
    int wave = tid >> 6, lane = tid & 63;
    int ql = lane & 31, hi = lane >> 5;
    // 2048 blocks = 8 xcd x 4 heads x 64 strips; alternate heavy/light
    int bid = blockIdx.x;
    int xcd = bid & 7, idx = bid >> 3;
    int bh = xcd * 4 + (idx >> 6);
    int j = idx & 63;
    int strip = (j & 1) ? (j >> 1) : 63 - (j >> 1);  // bijective on 0..63
    int q0 = strip * 32;

    const __bf16* Qp = Qf + (size_t)bh * 131072;
    const __bf16* Kp = Kf + (size_t)bh * 131072;
    const __bf16* Vp = Vf + (size_t)bh * 131072;

    const __bf16* qb = Qp + ((size_t)strip * 8 + hi) * 256 + ql * 8;
    bf16x8 qf[4];
#pragma unroll
    for (int st = 0; st < 4; st++) qf[st] = *(const bf16x8*)(qb + st * 512);

    bf16x8 ones;
#pragma unroll
    for (int jj = 0; jj < 8; jj++) ones[jj] = (__bf16)1.0f;

    f32x16 o0, o1, lsa;
#pragma unroll
    for (int r = 0; r < 16; r++) { o0[r] = 0.f; o1[r] = 0.f; lsa[r] = 0.f; }

    for (int c = wave; c < strip; c += 4)
        attn_chunk<false>(c, ql, hi, Kp, Vp, qf, ones, o0, o1, lsa);
    if ((strip & 3) == wave)
        attn_chunk<true>(strip, ql, hi, Kp, Vp, qf, ones, o0, o1, lsa);

    // ---- stage 1: waves {2,3} -> slabs; waves {0,1} add
    if (wave >= 2) {
        float* sl = &comb[wave - 2][lane][0];
#pragma unroll
        for (int r = 0; r < 16; r++) {
            sl[r] = o0[r]; sl[16 + r] = o1[r]; sl[32 + r] = lsa[r];
        }
    }
    __syncthreads();
    if (wave < 2) {
        const float* sl = &comb[wave][lane][0];
#pragma unroll
        for (int r = 0; r < 16; r++) {
            o0[r] += sl[r]; o1[r] += sl[16 + r]; lsa[r] += sl[32 + r];
        }
    }
    __syncthreads();
    // ---- stage 2: wave 1 -> slab 0; wave 0 adds + finalizes
    if (wave == 1) {
        float* sl = &comb[0][lane][0];
#pragma unroll
        for (int r = 0; r < 16; r++) {
            sl[r] = o0[r]; sl[16 + r] = o1[r]; sl[32 + r] = lsa[r];
        }
    }
    __syncthreads();
    if (wave == 0) {
        const float* sl = &comb[0][lane][0];
#pragma unroll
        for (int r = 0; r < 16; r++) {
            o0[r] += sl[r]; o1[r] += sl[16 + r]; lsa[r] += sl[32 + r];
        }
        int b = bh >> 4, h = bh & 15;
#pragma unroll
        for (int r = 0; r < 16; r++) {
            int crow = (r & 3) + 8 * (r >> 2) + 4 * hi;
            float inv;
            asm("v_rcp_f32 %0, %1" : "=v"(inv) : "v"(lsa[r]));
            size_t base = ((size_t)(b * 2048 + q0 + crow)) * 1024 + h * 64;
            Ob[base + ql] = (__bf16)(o0[r] * inv);
            Ob[base + 32 + ql] = (__bf16)(o1[r] * inv);
        }
    }
}

// ---------------------------------------------------------------------------
// launch
// ---------------------------------------------------------------------------
extern "C" void kernel_launch(void* const* d_in, const int* in_sizes, int n_in,
                              void* d_out, int out_size, void* d_ws, size_t ws_size,
                              hipStream_t stream) {
    const float* x = (const float*)d_in[0];       // (2, 2048, 1024)
    const float* w_qkv = (const float*)d_in[1];   // (1024, 3072)
    const float* w_out = (const float*)d_in[2];   // (1024, 1024)
    float* out = (float*)d_out;                   // (2, 2048, 1024)

    char* ws = (char*)d_ws;
    __bf16* xb    = (__bf16*)(ws);                        //  8 MB (4096x1024)
    __bf16* wqkvT = (__bf16*)(ws + (size_t)(8  << 20));   //  6 MB (3072x1024)
    __bf16* woutT = (__bf16*)(ws + (size_t)(14 << 20));   //  2 MB (1024x1024)
    __bf16* Qf    = (__bf16*)(ws + (size_t)(16 << 20));   //  8 MB
    __bf16* Kf    = (__bf16*)(ws + (size_t)(24 << 20));   //  8 MB
    __bf16* Vf    = (__bf16*)(ws + (size_t)(32 << 20));   //  8 MB
    __bf16* Ob    = (__bf16*)(ws + (size_t)(40 << 20));   //  8 MB (4096x1024)

    prep_all<<<8192, 256, 0, stream>>>(x, xb, w_qkv, wqkvT, w_out, woutT);
    // QKV projection: 256^2 8-phase kernel, conflict-free swizzle
    qkv_gemm8<<<192, 512, 0, stream>>>(wqkvT, xb, Qf, Kf, Vf);
    attn_fwd17<<<2048, 256, 0, stream>>>(Qf, Kf, Vf, Ob);
    // output projection (M=1024 feats, N=4096 tokens), BM=64 -> 512 blocks
    gemm_bt<0, 64><<<512, 256, 0, stream>>>(
        woutT, Ob, 1024, 4096, 1024, out);
}

// Round 22
// 94.725 us; speedup vs baseline: 1.0389x; 1.0389x over previous
//
#include <hip/hip_runtime.h>

typedef __attribute__((ext_vector_type(4))) float f32x4;
typedef __attribute__((ext_vector_type(16))) float f32x16;
typedef __attribute__((ext_vector_type(8))) __bf16 bf16x8;
typedef __attribute__((ext_vector_type(4))) __bf16 bf16x4;
typedef __attribute__((ext_vector_type(4))) unsigned u32x4;
typedef __attribute__((ext_vector_type(2))) unsigned u32x2;

static __device__ __forceinline__ f32x4 mfma16(bf16x8 a, bf16x8 b, f32x4 c) {
    return __builtin_amdgcn_mfma_f32_16x16x32_bf16(a, b, c, 0, 0, 0);
}
static __device__ __forceinline__ f32x16 mfma32(bf16x8 a, bf16x8 b, f32x16 c) {
    return __builtin_amdgcn_mfma_f32_32x32x16_bf16(a, b, c, 0, 0, 0);
}
static __device__ __forceinline__ unsigned pk_bf16(float a, float b) {
    unsigned lo = __builtin_bit_cast(unsigned short, (__bf16)a);
    unsigned hh = __builtin_bit_cast(unsigned short, (__bf16)b);
    return lo | (hh << 16);
}

// Q pre-scale: 1/sqrt(64) * log2(e)  (exp2 applied directly to S, shift-free)
#define QSCALE 0.18033688f
#define FENCE() asm volatile("" ::: "memory")
#define SYNCB()                          \
    do {                                 \
        FENCE();                         \
        __builtin_amdgcn_s_barrier();    \
        FENCE();                         \
    } while (0)

// ---------------------------------------------------------------------------
// 1) fused prep: x cvt -> bf16 (blocks 0..4095), w_qkv transpose
//    (4096..7167), w_out transpose (7168..8191)
// ---------------------------------------------------------------------------
__global__ __launch_bounds__(256) void prep_all(const float* __restrict__ x,
                                                __bf16* __restrict__ xb,
                                                const float* __restrict__ wq,
                                                __bf16* __restrict__ wqT,
                                                const float* __restrict__ wo,
                                                __bf16* __restrict__ woT) {
    __shared__ float t[32][33];
    int bid = blockIdx.x, tid = threadIdx.x;
    if (bid < 4096) {
        int i = bid * 256 + tid;
        f32x4 v = ((const f32x4*)x)[i];
        bf16x4 o;
#pragma unroll
        for (int j = 0; j < 4; j++) o[j] = (__bf16)v[j];
        ((bf16x4*)xb)[i] = o;
        return;
    }
    const float* in;
    __bf16* out;
    int R, C, bx, by;
    if (bid < 4096 + 3072) {
        int b2 = bid - 4096;
        in = wq; out = wqT; R = 1024; C = 3072;
        bx = (b2 % 96) * 32; by = (b2 / 96) * 32;
    } else {
        int b2 = bid - 7168;
        in = wo; out = woT; R = 1024; C = 1024;
        bx = (b2 % 32) * 32; by = (b2 / 32) * 32;
    }
    int tx = tid & 31, ty = tid >> 5;  // 32 x 8
#pragma unroll
    for (int k = 0; k < 32; k += 8)
        t[ty + k][tx] = in[(size_t)(by + ty + k) * C + bx + tx];
    __syncthreads();
#pragma unroll
    for (int k = 0; k < 32; k += 8)
        out[(size_t)(bx + ty + k) * R + by + tx] = (__bf16)t[tx][ty + k];
}

// ---------------------------------------------------------------------------
// 3a) QKV GEMM, 256x256 tile, 8-phase counted-vmcnt schedule, conflict-free
//     LDS swizzle f(r) = (r>>1)&3 (round-17 proven: bank conflicts -> 0).
// ---------------------------------------------------------------------------
__global__ __launch_bounds__(512, 2) void qkv_gemm8(const __bf16* __restrict__ A,
                                                    const __bf16* __restrict__ Bt,
                                                    __bf16* __restrict__ Qf,
                                                    __bf16* __restrict__ Kf,
                                                    __bf16* __restrict__ Vf) {
    const int K = 1024, NT = 16, MT = 12;
    __shared__ __attribute__((aligned(16))) __bf16 smem[65536];  // 128 KiB
    int tid = threadIdx.x;
    int w = tid >> 6, lane = tid & 63;
    int lrow = lane & 15, lgrp = lane >> 4;
    int wm = w >> 2, wn = w & 3;
    int bid = blockIdx.x;
    int swz = (bid & 7) * 24 + (bid >> 3);          // 192 % 8 == 0: bijective
    int m0 = (swz % MT) * 256, n0 = (swz / MT) * 256;

    int schunk = ((lane & 3) ^ ((lane >> 3) & 3)) * 8;  // elements
    const __bf16* aS[2];
    const __bf16* bS[2];
    int dstRow[2];
#pragma unroll
    for (int l = 0; l < 2; l++) {
        int r = w * 32 + l * 16 + (lane >> 2);
        aS[l] = A + (size_t)(m0 + r) * K + schunk;
        bS[l] = Bt + (size_t)(n0 + r) * K + schunk;
        dstRow[l] = (w * 32 + l * 16) * 64;  // byte offset of row block
    }

    auto STAGE = [&](int h, int tt) {
        int tc = tt < NT ? tt : NT - 1;
        int op = h & 1, kh = h >> 1;
        int base = ((tt & 1) << 16) + (kh << 15) + (op << 14);
#pragma unroll
        for (int l = 0; l < 2; l++) {
            const __bf16* src = (op ? bS[l] : aS[l]) + tc * 64 + kh * 32;
            __builtin_amdgcn_global_load_lds(
                (const __attribute__((address_space(1))) void*)src,
                (__attribute__((address_space(3))) void*)(smem +
                                                          ((base + dstRow[l]) >> 1)),
                16, 0, 0);
        }
    };

    int swzsel = (lgrp ^ ((lrow >> 1) & 3)) << 4;  // byte offset of chunk slot
    auto RDA = [&](int buf, int kk, int row) {
        int off = (buf << 16) + (kk << 15) + row * 64 + swzsel;
        return *(const bf16x8*)(smem + (off >> 1));
    };
    auto RDB = [&](int buf, int kk, int row) {
        int off = (buf << 16) + (kk << 15) + 16384 + row * 64 + swzsel;
        return *(const bf16x8*)(smem + (off >> 1));
    };

    f32x4 acc[8][4];
#pragma unroll
    for (int i = 0; i < 8; i++)
#pragma unroll
        for (int j = 0; j < 4; j++) acc[i][j] = (f32x4){0.f, 0.f, 0.f, 0.f};
    bf16x8 bfr[4];

    STAGE(0, 0); STAGE(1, 0); STAGE(2, 0); STAGE(3, 0);
    STAGE(0, 1); STAGE(1, 1);
    asm volatile("s_waitcnt vmcnt(8)" ::: "memory");
    SYNCB();

#define PH(T, KKv, MHv, SH, ST, DOVM)                                          \
    {                                                                          \
        bf16x8 af[4];                                                          \
        if (MHv == 0) {                                                        \
            _Pragma("unroll") for (int nt = 0; nt < 4; nt++) bfr[nt] =         \
                RDB((T) & 1, KKv, wn * 64 + nt * 16 + lrow);                   \
        }                                                                      \
        _Pragma("unroll") for (int i = 0; i < 4; i++) af[i] =                  \
            RDA((T) & 1, KKv, wm * 128 + (MHv * 4 + i) * 16 + lrow);           \
        STAGE(SH, ST);                                                         \
        if (DOVM) asm volatile("s_waitcnt vmcnt(8)" ::: "memory");             \
        SYNCB();                                                               \
        asm volatile("s_waitcnt lgkmcnt(0)" ::: "memory");                     \
        __builtin_amdgcn_sched_barrier(0);                                     \
        __builtin_amdgcn_s_setprio(1);                                         \
        _Pragma("unroll") for (int i = 0; i < 4; i++)                          \
            _Pragma("unroll") for (int nt = 0; nt < 4; nt++)                   \
                acc[MHv * 4 + i][nt] =                                         \
                    mfma16(af[i], bfr[nt], acc[MHv * 4 + i][nt]);              \
        __builtin_amdgcn_s_setprio(0);                                         \
        SYNCB();                                                               \
    }

#pragma unroll 2
    for (int t = 0; t < NT; ++t) {
        PH(t, 0, 0, 2, t + 1, 0);
        PH(t, 0, 1, 3, t + 1, 1);
        PH(t, 1, 0, 0, t + 2, 0);
        PH(t, 1, 1, 1, t + 2, 1);
    }
#undef PH

    asm volatile("s_waitcnt vmcnt(0)" ::: "memory");
    SYNCB();

#pragma unroll
    for (int mt = 0; mt < 8; mt++) {
#pragma unroll
        for (int nt = 0; nt < 4; nt++) {
            int f0 = m0 + wm * 128 + mt * 16 + lgrp * 4;
            int t = n0 + wn * 64 + nt * 16 + lrow;
            int which = f0 >> 10, hn = f0 & 1023;
            int h = hn >> 6, d0 = hn & 63;
            int b = t >> 11, li = t & 2047;
            int bh = b * 16 + h, c = li >> 5, tl = li & 31;
            size_t bhbase = (size_t)bh * 131072;
            if (which == 2) {
                int ks = tl >> 4, hv = (tl >> 3) & 1, jv = tl & 7;
                size_t base =
                    bhbase + ((size_t)(c * 4 + ks * 2 + hv) * 64 + d0) * 8 + jv;
#pragma unroll
                for (int r = 0; r < 4; r++)
                    Vf[base + (size_t)r * 8] = (__bf16)acc[mt][nt][r];
            } else {
                int st = d0 >> 4, hv = (d0 >> 3) & 1, j0 = d0 & 7;
                size_t idx =
                    bhbase + ((size_t)(c * 8 + st * 2 + hv) * 32 + tl) * 8 + j0;
                bf16x4 pv;
                if (which == 0) {
#pragma unroll
                    for (int r = 0; r < 4; r++)
                        pv[r] = (__bf16)(acc[mt][nt][r] * QSCALE);
                    *(bf16x4*)(Qf + idx) = pv;
                } else {
#pragma unroll
                    for (int r = 0; r < 4; r++) pv[r] = (__bf16)acc[mt][nt][r];
                    *(bf16x4*)(Kf + idx) = pv;
                }
            }
        }
    }
}

// ---------------------------------------------------------------------------
// 3b) bf16 GEMM (proven 2-barrier structure), BM=64 x 128, out projection.
// ---------------------------------------------------------------------------
#define BN 128
#define BKG 64

template <int MODE, int BMv>
__global__ __launch_bounds__(256) void gemm_bt(const __bf16* __restrict__ A,
                                               const __bf16* __restrict__ Bt,
                                               int M, int N, int K,
                                               float* __restrict__ Cout) {
    constexpr int nMt = BMv / 32;
    __shared__ __attribute__((aligned(16))) __bf16 As[BMv * BKG];
    __shared__ __attribute__((aligned(16))) __bf16 Bs[BN * BKG];
    int tid = threadIdx.x;
    int wave = tid >> 6, lane = tid & 63;
    int lrow = lane & 15, lgrp = lane >> 4;
    int bid = blockIdx.x;
    int chunk = gridDim.x >> 3;
    int swz = (bid & 7) * chunk + (bid >> 3);
    int nbx = N >> 7;
    int m0 = (swz / nbx) * BMv;
    int n0 = (swz % nbx) * BN;
    int wm = (wave >> 1) * (BMv / 2);
    int wn = (wave & 1) * 64;

    f32x4 acc[nMt][4];
#pragma unroll
    for (int i = 0; i < nMt; i++)
#pragma unroll
        for (int j = 0; j < 4; j++) acc[i][j] = (f32x4){0.f, 0.f, 0.f, 0.f};

    int srow = tid >> 3;
    int gch = (tid & 7) ^ (srow & 7);
    const __bf16* aSrc = A + (size_t)(m0 + srow) * K + gch * 8;
    const __bf16* bSrc = Bt + (size_t)(n0 + srow) * K + gch * 8;

    for (int k0 = 0; k0 < K; k0 += BKG) {
#pragma unroll
        for (int c = 0; c < BMv / 32; c++) {
            __builtin_amdgcn_global_load_lds(
                (const __attribute__((address_space(1))) void*)(aSrc + k0 + (size_t)c * 32 * K),
                (__attribute__((address_space(3))) void*)(As + (c * 256 + wave * 64) * 8),
                16, 0, 0);
        }
#pragma unroll
        for (int c = 0; c < 4; c++) {
            __builtin_amdgcn_global_load_lds(
                (const __attribute__((address_space(1))) void*)(bSrc + k0 + (size_t)c * 32 * K),
                (__attribute__((address_space(3))) void*)(Bs + (c * 256 + wave * 64) * 8),
                16, 0, 0);
        }
        __syncthreads();
#pragma unroll
        for (int kk = 0; kk < 2; kk++) {
            bf16x8 af[nMt], bfr[4];
#pragma unroll
            for (int mt = 0; mt < nMt; mt++) {
                int row = wm + mt * 16 + lrow;
                int slot = row * 8 + ((4 * kk + lgrp) ^ (row & 7));
                af[mt] = *(const bf16x8*)(As + slot * 8);
            }
#pragma unroll
            for (int nt = 0; nt < 4; nt++) {
                int row = wn + nt * 16 + lrow;
                int slot = row * 8 + ((4 * kk + lgrp) ^ (row & 7));
                bfr[nt] = *(const bf16x8*)(Bs + slot * 8);
            }
#pragma unroll
            for (int mt = 0; mt < nMt; mt++)
#pragma unroll
                for (int nt = 0; nt < 4; nt++)
                    acc[mt][nt] = mfma16(af[mt], bfr[nt], acc[mt][nt]);
        }
        __syncthreads();
    }

#pragma unroll
    for (int mt = 0; mt < nMt; mt++) {
#pragma unroll
        for (int nt = 0; nt < 4; nt++) {
            int f0 = m0 + wm + mt * 16 + lgrp * 4;
            int t = n0 + wn + nt * 16 + lrow;
            *(f32x4*)(Cout + (size_t)t * M + f0) = acc[mt][nt];
        }
    }
}

// ---------------------------------------------------------------------------
// 4) Causal flash attention v15 (round-18 proven, heavy-first dispatch):
//    swapped-QK^T, 32x32x16 MFMA, fragment-swizzled Q/K/V, fused exp2->pack,
//    MFMA row-sum via ones-operand, two-stage f32 combine tree (25.1 KB LDS).
// ---------------------------------------------------------------------------
template <bool MASKED>
static __device__ __forceinline__ void attn_chunk(
    int c, int ql, int hi, const __bf16* __restrict__ Kp,
    const __bf16* __restrict__ Vp, const bf16x8 (&qf)[4], bf16x8 ones,
    f32x16& o0, f32x16& o1, f32x16& lsa) {
    const __bf16* kb = Kp + ((size_t)c * 8 + hi) * 256 + ql * 8;
    bf16x8 kf[4];
#pragma unroll
    for (int st = 0; st < 4; st++) kf[st] = *(const bf16x8*)(kb + st * 512);
    const __bf16* vb = Vp + ((size_t)c * 4 + hi) * 512 + ql * 8;
    bf16x8 v00 = *(const bf16x8*)(vb);
    bf16x8 v01 = *(const bf16x8*)(vb + 256);
    bf16x8 v10 = *(const bf16x8*)(vb + 1024);
    bf16x8 v11 = *(const bf16x8*)(vb + 1280);

    f32x16 sa;
#pragma unroll
    for (int r = 0; r < 16; r++) sa[r] = 0.f;
#pragma unroll
    for (int st = 0; st < 4; st++) sa = mfma32(kf[st], qf[st], sa);

    // fused exp2 + pack (no p[16] array; identical values/order)
    unsigned w[8];
#pragma unroll
    for (int i = 0; i < 8; i++) {
        float a = sa[2 * i], b = sa[2 * i + 1];
        if (MASKED) {
            int ra = 2 * i, rb = 2 * i + 1;
            if (((ra & 3) + 8 * (ra >> 2) + 4 * hi) > ql) a = -1e30f;
            if (((rb & 3) + 8 * (rb >> 2) + 4 * hi) > ql) b = -1e30f;
        }
        w[i] = pk_bf16(__builtin_amdgcn_exp2f(a), __builtin_amdgcn_exp2f(b));
    }
    u32x2 r02 = __builtin_amdgcn_permlane32_swap(w[0], w[2], false, false);
    u32x2 r13 = __builtin_amdgcn_permlane32_swap(w[1], w[3], false, false);
    u32x2 r46 = __builtin_amdgcn_permlane32_swap(w[4], w[6], false, false);
    u32x2 r57 = __builtin_amdgcn_permlane32_swap(w[5], w[7], false, false);
    bf16x8 pa0 = __builtin_bit_cast(bf16x8, (u32x4){r02[0], r13[0], r02[1], r13[1]});
    bf16x8 pa1 = __builtin_bit_cast(bf16x8, (u32x4){r46[0], r57[0], r46[1], r57[1]});

    o0 = mfma32(pa0, v00, o0);
    o1 = mfma32(pa0, v01, o1);
    lsa = mfma32(pa0, ones, lsa);
    o0 = mfma32(pa1, v10, o0);
    o1 = mfma32(pa1, v11, o1);
    lsa = mfma32(pa1, ones, lsa);
}

__global__ __launch_bounds__(256, 4) void attn_fwd15(const __bf16* __restrict__ Qf,
                                                     const __bf16* __restrict__ Kf,
                                                     const __bf16* __restrict__ Vf,
                                                     __bf16* __restrict__ Ob) {
    __shared__ float comb[2][64][49];  // 25.1 KB, f32 precision
    int tid = threadIdx.x;
    int wave = tid >> 6, lane = tid & 63;
    int ql = lane & 31, hi = lane >> 5;
    // XCD swizzle: 2048 blocks = 8 xcd x 4 heads x 64 strips (heavy first)
    int bid = blockIdx.x;
    int xcd = bid & 7, idx = bid >> 3;
    int bh = xcd * 4 + (idx >> 6);
    int strip = 63 - (idx & 63);
    int q0 = strip * 32;

    const __bf16* Qp = Qf + (size_t)bh * 131072;
    const __bf16* Kp = Kf + (size_t)bh * 131072;
    const __bf16* Vp = Vf + (size_t)bh * 131072;

    const __bf16* qb = Qp + ((size_t)strip * 8 + hi) * 256 + ql * 8;
    bf16x8 qf[4];
#pragma unroll
    for (int st = 0; st < 4; st++) qf[st] = *(const bf16x8*)(qb + st * 512);

    bf16x8 ones;
#pragma unroll
    for (int j = 0; j < 8; j++) ones[j] = (__bf16)1.0f;

    f32x16 o0, o1, lsa;
#pragma unroll
    for (int r = 0; r < 16; r++) { o0[r] = 0.f; o1[r] = 0.f; lsa[r] = 0.f; }

    for (int c = wave; c < strip; c += 4)
        attn_chunk<false>(c, ql, hi, Kp, Vp, qf, ones, o0, o1, lsa);
    if ((strip & 3) == wave)
        attn_chunk<true>(strip, ql, hi, Kp, Vp, qf, ones, o0, o1, lsa);

    // ---- stage 1: waves {2,3} -> slabs; waves {0,1} add
    if (wave >= 2) {
        float* sl = &comb[wave - 2][lane][0];
#pragma unroll
        for (int r = 0; r < 16; r++) {
            sl[r] = o0[r]; sl[16 + r] = o1[r]; sl[32 + r] = lsa[r];
        }
    }
    __syncthreads();
    if (wave < 2) {
        const float* sl = &comb[wave][lane][0];
#pragma unroll
        for (int r = 0; r < 16; r++) {
            o0[r] += sl[r]; o1[r] += sl[16 + r]; lsa[r] += sl[32 + r];
        }
    }
    __syncthreads();
    // ---- stage 2: wave 1 -> slab 0; wave 0 adds + finalizes
    if (wave == 1) {
        float* sl = &comb[0][lane][0];
#pragma unroll
        for (int r = 0; r < 16; r++) {
            sl[r] = o0[r]; sl[16 + r] = o1[r]; sl[32 + r] = lsa[r];
        }
    }
    __syncthreads();
    if (wave == 0) {
        const float* sl = &comb[0][lane][0];
#pragma unroll
        for (int r = 0; r < 16; r++) {
            o0[r] += sl[r]; o1[r] += sl[16 + r]; lsa[r] += sl[32 + r];
        }
        int b = bh >> 4, h = bh & 15;
#pragma unroll
        for (int r = 0; r < 16; r++) {
            int crow = (r & 3) + 8 * (r >> 2) + 4 * hi;
            float inv;
            asm("v_rcp_f32 %0, %1" : "=v"(inv) : "v"(lsa[r]));
            size_t base = ((size_t)(b * 2048 + q0 + crow)) * 1024 + h * 64;
            Ob[base + ql] = (__bf16)(o0[r] * inv);
            Ob[base + 32 + ql] = (__bf16)(o1[r] * inv);
        }
    }
}

// ---------------------------------------------------------------------------
// launch
// ---------------------------------------------------------------------------
extern "C" void kernel_launch(void* const* d_in, const int* in_sizes, int n_in,
                              void* d_out, int out_size, void* d_ws, size_t ws_size,
                              hipStream_t stream) {
    const float* x = (const float*)d_in[0];       // (2, 2048, 1024)
    const float* w_qkv = (const float*)d_in[1];   // (1024, 3072)
    const float* w_out = (const float*)d_in[2];   // (1024, 1024)
    float* out = (float*)d_out;                   // (2, 2048, 1024)

    char* ws = (char*)d_ws;
    __bf16* xb    = (__bf16*)(ws);                        //  8 MB (4096x1024)
    __bf16* wqkvT = (__bf16*)(ws + (size_t)(8  << 20));   //  6 MB (3072x1024)
    __bf16* woutT = (__bf16*)(ws + (size_t)(14 << 20));   //  2 MB (1024x1024)
    __bf16* Qf    = (__bf16*)(ws + (size_t)(16 << 20));   //  8 MB
    __bf16* Kf    = (__bf16*)(ws + (size_t)(24 << 20));   //  8 MB
    __bf16* Vf    = (__bf16*)(ws + (size_t)(32 << 20));   //  8 MB
    __bf16* Ob    = (__bf16*)(ws + (size_t)(40 << 20));   //  8 MB (4096x1024)

    prep_all<<<8192, 256, 0, stream>>>(x, xb, w_qkv, wqkvT, w_out, woutT);
    // QKV projection: 256^2 8-phase kernel, conflict-free swizzle
    qkv_gemm8<<<192, 512, 0, stream>>>(wqkvT, xb, Qf, Kf, Vf);
    attn_fwd15<<<2048, 256, 0, stream>>>(Qf, Kf, Vf, Ob);
    // output projection (M=1024 feats, N=4096 tokens), BM=64 -> 512 blocks
    gemm_bt<0, 64><<<512, 256, 0, stream>>>(
        woutT, Ob, 1024, 4096, 1024, out);
}